// Round 3
// baseline (9.724 us; speedup 1.0000x reference)
//
#include <hip/hip_runtime.h>

// MPA forward, M=4, F=4, V=6 — launch-latency-bound.
// Single wave (64 lanes), ZERO barriers, ZERO LDS. All global loads have
// data-independent addresses (issued in one wall); data-dependent gathers are
// register select-chains; cross-lane A-value exchange via ds_bpermute.
//
// Algebra: 0.25*IFV / (0.25*sum) -> IFV/sum (constants cancel). Incidence of
// this graph guarantees every (fx,v) read in the output phase is produced in
// phase 1 (verified against FN/VN tables).

__device__ __forceinline__ float sel6f(float r0, float r1, float r2, float r3,
                                       float r4, float r5, int j) {
    float x = r0;
    x = (j == 1) ? r1 : x;
    x = (j == 2) ? r2 : x;
    x = (j == 3) ? r3 : x;
    x = (j == 4) ? r4 : x;
    x = (j == 5) ? r5 : x;
    return x;
}

__device__ __forceinline__ int sel4i(int x0, int x1, int x2, int x3, int j) {
    int x = x0;
    x = (j == 1) ? x1 : x;
    x = (j == 2) ? x2 : x;
    x = (j == 3) ? x3 : x;
    return x;
}

__device__ __forceinline__ float bperm(int lane, float v) {
    return __int_as_float(
        __builtin_amdgcn_ds_bpermute(lane << 2, __float_as_int(v)));
}

__global__ __launch_bounds__(64) void mpa_kernel(
    const float* __restrict__ IVF,   // (4,4,6) = 96, a*24 + f*6 + v
    const int*   __restrict__ VN,    // (2,6)
    const int*   __restrict__ mPtr,  // scalar
    const int*   __restrict__ nPtr,  // scalar
    const int*   __restrict__ FN,    // (4,3)
    const float* __restrict__ fa,    // (4,4,4,4), f*64 + i*16 + j*4 + k
    const float* __restrict__ w0,    // (4,4,6)
    float*       __restrict__ out)   // (4,4,6)
{
    const int l = threadIdx.x;

    // ---- lane identities (compile/lane-constant, no data deps) -----------
    const int kind = (l >= 32) ? 2 : (l >> 4);   // producer lane: kind*16+a*4+f
    const int a1   = (l >> 2) & 3;
    const int f1   = l & 3;

    const int o1 = l;                 // output index #1 (0..63)
    const int o2 = 64 + (l & 31);     // output index #2 (64..95), stored by l<32

    const int a2_1 = o1 / 24, rem1 = o1 - a2_1 * 24;
    const int f2_1 = rem1 / 6, v2_1 = rem1 - f2_1 * 6;
    const int a2_2 = o2 / 24, rem2 = o2 - a2_2 * 24;
    const int f2_2 = rem2 / 6, v2_2 = rem2 - f2_2 * 6;

    // ---- ONE wall of independent global loads ----------------------------
    const int mv = mPtr[0];
    const int nv = nPtr[0];

    int fn[12];
    #pragma unroll
    for (int k = 0; k < 12; ++k) fn[k] = FN[k];

    // all 6 IVF columns for (row i, face f1): breaks the FN->gather dependency
    float row[4][6];
    #pragma unroll
    for (int i = 0; i < 4; ++i)
        #pragma unroll
        for (int j = 0; j < 6; ++j)
            row[i][j] = IVF[i * 24 + f1 * 6 + j];

    // the 16 fa values this producer lane needs (lane-dependent addr only)
    float fr[16];
    #pragma unroll
    for (int c = 0; c < 4; ++c)
        #pragma unroll
        for (int b = 0; b < 4; ++b) {
            const int i0 = c * 16 + a1 * 4 + b;   // kind 0: fa[f,c,a,b]
            const int i1 = c * 16 + b * 4 + a1;   // kind 1: fa[f,c,b,a]
            const int i2 = a1 * 16 + b * 4 + c;   // kind 2: fa[f,a,b,c]
            const int off = (kind == 0) ? i0 : ((kind == 1) ? i1 : i2);
            fr[c * 4 + b] = fa[f1 * 64 + off];
        }

    const float iv1 = IVF[o1], wv1 = w0[o1];
    const float iv2 = IVF[o2], wv2 = w0[o2];
    const int va1 = VN[v2_1], vb1 = VN[6 + v2_1];
    const int va2 = VN[v2_2], vb2 = VN[6 + v2_2];

    // ---- Phase 1: per-lane A-value, pure register math -------------------
    const int j0 = sel4i(fn[0], fn[3], fn[6], fn[9],  f1);
    const int j1 = sel4i(fn[1], fn[4], fn[7], fn[10], f1);
    const int j2 = sel4i(fn[2], fn[5], fn[8], fn[11], f1);
    const int jb = (kind == 0) ? j1 : j0;
    const int jc = (kind == 2) ? j1 : j2;

    float gb[4], gc[4];
    #pragma unroll
    for (int i = 0; i < 4; ++i) {
        gb[i] = sel6f(row[i][0], row[i][1], row[i][2],
                      row[i][3], row[i][4], row[i][5], jb);
        gc[i] = sel6f(row[i][0], row[i][1], row[i][2],
                      row[i][3], row[i][4], row[i][5], jc);
    }

    float acc = 0.0f;
    #pragma unroll
    for (int c = 0; c < 4; ++c)
        #pragma unroll
        for (int b = 0; b < 4; ++b)
            acc += gb[b] * gc[c] * fr[c * 4 + b];

    // ---- Phase 2: cross-lane exchange + output, fully branchless ---------
    // (all 64 lanes active at every bpermute)
    float res[2];
    const int  a2v[2] = {a2_1, a2_2};
    const int  f2v[2] = {f2_1, f2_2};
    const int  v2v[2] = {v2_1, v2_2};
    const int  vav[2] = {va1, va2};
    const int  vbv[2] = {vb1, vb2};
    const float ivv[2] = {iv1, iv2};
    const float wvv[2] = {wv1, wv2};

    #pragma unroll
    for (int q = 0; q < 2; ++q) {
        const int f2 = f2v[q], v2 = v2v[q], a2 = a2v[q];
        const int va = vav[q], vb = vbv[q];
        const int fx = (f2 == va) ? vb : va;
        const int fnA = sel4i(fn[0], fn[3], fn[6], fn[9],  fx);
        const int fnB = sel4i(fn[1], fn[4], fn[7], fn[10], fx);
        const int kx  = (fnA == v2) ? 0 : ((fnB == v2) ? 1 : 2);
        const int base = kx * 16 + fx;            // producer lane for a=0
        const float p0 = bperm(base + 0,  acc);
        const float p1 = bperm(base + 4,  acc);
        const float p2 = bperm(base + 8,  acc);
        const float p3 = bperm(base + 12, acc);
        const float sum = (p0 + p1) + (p2 + p3);
        float num = p0;
        num = (a2 == 1) ? p1 : num;
        num = (a2 == 2) ? p2 : num;
        num = (a2 == 3) ? p3 : num;
        const bool incident = (f2 == va) || (f2 == vb);
        const float val = incident ? (num / sum) : ivv[q];
        res[q] = (mv >= nv) ? ivv[q] : val * wvv[q];
    }

    // ---- stores (only divergence in the kernel) --------------------------
    out[o1] = res[0];
    if (l < 32) out[o2] = res[1];
}

extern "C" void kernel_launch(void* const* d_in, const int* in_sizes, int n_in,
                              void* d_out, int out_size, void* d_ws, size_t ws_size,
                              hipStream_t stream) {
    (void)in_sizes; (void)n_in; (void)d_ws; (void)ws_size; (void)out_size;
    const float* IVF = (const float*)d_in[3];
    const int*   VN  = (const int*)  d_in[4];
    const int*   m   = (const int*)  d_in[5];
    const int*   n   = (const int*)  d_in[6];
    const int*   FN  = (const int*)  d_in[7];
    const float* fa  = (const float*)d_in[8];
    const float* w0  = (const float*)d_in[9];
    float*       out = (float*)d_out;

    mpa_kernel<<<1, 64, 0, stream>>>(IVF, VN, m, n, FN, fa, w0, out);
}